// Round 5
// baseline (404.576 us; speedup 1.0000x reference)
//
#include <hip/hip_runtime.h>

#define HDIM   64
#define TSTEPS 5
#define WAVES  8
#define BLOCK  (WAVES * 64)     // 512 threads
#define EPW    16               // batch per wave = MFMA M
#define EPB    (WAVES * EPW)    // 128 batch per block

typedef _Float16 f16x8 __attribute__((ext_vector_type(8)));
typedef float    f32x4 __attribute__((ext_vector_type(4)));

#define L2E 1.44269504088896340736f   // log2(e)

// Native 1-ulp ops (trans pipe, quarter rate -> minimize count)
__device__ __forceinline__ float rcp_(float x) { return __builtin_amdgcn_rcpf(x); }
__device__ __forceinline__ float ex2_(float x) { return __builtin_amdgcn_exp2f(x); }

// Gates as D[m=batch e][n=gate row j'] = A[e][k] * B[k][j'] + C(bias + x*W_ih)
// A = h^T (per-timestep, rebuilt), B = W_hh^T (staged once, PRE-SCALED by
// log2e for i/f/o columns and 2*log2e for g columns so activations use raw
// v_exp_f32 = 2^x with no multiply).
// 16x16x32 f16 layouts (verified, absmax 9.8e-4):
//   A-frag: lane holds A[m=lane&15][k = kh*32 + (lane>>4)*8 + i], i=0..7
//   B-frag: lane holds B[k = kh*32 + (lane>>4)*8 + i][n = ntile*16 + (lane&15)]
//   C/D:    lane holds D[m = (lane>>4)*4 + reg][n = ntile*16 + (lane&15)]
//
// Activation: LOCAL fusions only, each temp consumed within 2-3 ops:
//   it = i*tanh(g)*2L2E = 2L2E*(Eg-1) * rcp((1+Ei)*(Eg+1))   (1 rcp, was 2)
//   sf = rcp(1+Ef)
//   cs = fmaf(sf, c, it)          [c kept in 2L2E-scaled domain]
//   hn = o*tanh(c) = (Ec-1) * rcp((1+Eo)*(Ec+1))             (1 rcp, was 2)
// -> 5 ex2 + 3 rcp per hidden unit (round-0 had 5 ex2 + 5 rcp).
//
// REGISTER/OCCUPANCY MODEL (rounds 1-4, do not regress):
//   VGPR cap ~= 256/launch_bounds_arg2: (1024,8)->32, (512,4)->64, (512,2)->128.
//   VGPR pool = 512/SIMD: <=64 regs -> 8 waves/SIMD, 65..128 -> 4, 129..256 -> 2.
//   LDS 51.2 KB/block caps residency at 3 blocks/CU = 24 waves/CU = 6 waves/SIMD,
//   which needs VGPR <= 85. Hence arg2=3 (cap ~85): enough headroom for the
//   fused activations (r4 allocated 124 only because arg2=2 allowed it; live
//   set is ~60-80), while keeping full LDS-bound occupancy.
//   Round-1: arg2=8 -> 32-reg cap -> full spill (2.8 GB scratch, 8x slower).
//   Rounds 2/3: >cap live set (hoisted coeff arrays) -> ~1.4 GB scratch.
//   Round-4: arg2=2 -> VGPR 124 -> occupancy 36%->19%, dur 106->124 us.
//   NO register hoisting of wih/cb coeff arrays; LDS broadcasts are cheap.
__global__ __launch_bounds__(BLOCK, 3) void lstm_mfma_kernel(
    const float* __restrict__ x,      // [B, T, 1]
    const float* __restrict__ W_ih,   // [256, 1]
    const float* __restrict__ W_hh,   // [256, 64]
    const float* __restrict__ b_ih,   // [256]
    const float* __restrict__ b_hh,   // [256]
    const float* __restrict__ W_fc,   // [1, 64]
    const float* __restrict__ b_fc,   // [1]
    float* __restrict__ out,          // [B, 1]
    int B)
{
    __shared__ _Float16 Wf[2048 * 8];          // 32 KB, B-fragments, fragment-linear
    __shared__ _Float16 hbuf[WAVES * 1024];    // 16 KB, per-wave h A-fragments
    __shared__ float    wih_s[256];            // 1 KB (pre-scaled)
    __shared__ float    cb_s[256];             // 1 KB (pre-scaled b_ih + b_hh)

    const int tid = threadIdx.x;

    // ---- one-time staging: W_hh -> fp16 B-fragments, log2e pre-scaled ----
    #pragma unroll
    for (int s0 = 0; s0 < 2048; s0 += BLOCK) {
        const int s  = s0 + tid;
        const int ln = s & 63;
        const int kh = (s >> 6) & 1;
        const int n  = s >> 7;                             // N-tile 0..15, gate G = n>>2
        const float scl = ((n >> 2) == 2) ? (2.0f * L2E) : L2E;
        const int j  = n * 16 + (ln & 15);                 // gate row j'
        const int k0 = kh * 32 + ((ln >> 4) & 3) * 8;      // hidden k
        const float* src = W_hh + j * HDIM + k0;
        #pragma unroll
        for (int i = 0; i < 8; i++)
            Wf[s * 8 + i] = (_Float16)(src[i] * scl);
    }
    if (tid < 256) {
        const float scl = ((tid >> 6) == 2) ? (2.0f * L2E) : L2E;
        wih_s[tid] = W_ih[tid] * scl;
        cb_s[tid]  = (b_ih[tid] + b_hh[tid]) * scl;
    }
    __syncthreads();   // only barrier in the kernel

    const int lane = tid & 63;
    const int wave = tid >> 6;
    const int m    = lane & 15;    // C-layout column (gate-row local) / A row m
    const int q    = lane >> 4;    // quad
    const int eg0  = (blockIdx.x * WAVES + wave) * EPW;

    _Float16* hb = hbuf + wave * 1024;

    // x base pointers for this lane's 4 batch rows (hoisted; per-t load is imm offset)
    const float* xp[4];
    #pragma unroll
    for (int r = 0; r < 4; r++) {
        int e = eg0 + q * 4 + r;
        if (e >= B) e = B - 1;
        xp[r] = x + (long)e * TSTEPS;
    }

    float c[16];    // cell state, SCALED by 2*log2e; [gr*4+r] <-> (j=gr*16+m, e=q*4+r)
    float hv[16];   // last hidden state (unscaled), same indexing

    for (int t = 0; t < TSTEPS; t++) {
        float xt[4];
        #pragma unroll
        for (int r = 0; r < 4; r++) xt[r] = xp[r][t];

        // h A-fragments from previous timestep (same-wave LDS, no barrier needed)
        f16x8 hA0, hA1;
        if (t > 0) {
            hA0 = *(const f16x8*)(hb + lane * 8);          // kh = 0
            hA1 = *(const f16x8*)(hb + 512 + lane * 8);    // kh = 1
        }

        #pragma unroll
        for (int gr = 0; gr < 4; gr++) {       // j' chunk: j = gr*16 + m
            // C-init: bias + x*W_ih directly as the MFMA C operand
            float wihv[4], cbv[4];
            #pragma unroll
            for (int G = 0; G < 4; G++) {
                wihv[G] = wih_s[G * 64 + gr * 16 + m];   // broadcast, conflict-free
                cbv[G]  = cb_s[G * 64 + gr * 16 + m];
            }
            f32x4 ag[4];
            #pragma unroll
            for (int G = 0; G < 4; G++)
                #pragma unroll
                for (int r = 0; r < 4; r++)
                    ag[G][r] = fmaf(xt[r], wihv[G], cbv[G]);

            if (t > 0) {
                #pragma unroll
                for (int G = 0; G < 4; G++) {
                    const int n = G * 4 + gr;
                    f16x8 w0 = *(const f16x8*)(Wf + (n * 2 + 0) * 512 + lane * 8);
                    f16x8 w1 = *(const f16x8*)(Wf + (n * 2 + 1) * 512 + lane * 8);
                    ag[G] = __builtin_amdgcn_mfma_f32_16x16x32_f16(hA0, w0, ag[G], 0, 0, 0);
                    ag[G] = __builtin_amdgcn_mfma_f32_16x16x32_f16(hA1, w1, ag[G], 0, 0, 0);
                }
            }

            #pragma unroll
            for (int r = 0; r < 4; r++) {
                const int u = gr * 4 + r;
                // 5 ex2 + 3 rcp, all short local chains
                const float Ei = ex2_(-ag[0][r]);
                const float Eg = ex2_(ag[2][r]);
                const float it = (2.0f * L2E) * (Eg - 1.0f) *
                                 rcp_((1.0f + Ei) * (Eg + 1.0f));
                const float Ef = ex2_(-ag[1][r]);
                const float sf = rcp_(1.0f + Ef);
                float cs = it;
                if (t > 0) cs = fmaf(sf, c[u], cs);
                c[u] = cs;                                    // scaled domain
                const float Eo = ex2_(-ag[3][r]);
                const float Ec = ex2_(cs);
                const float hn = (Ec - 1.0f) * rcp_((1.0f + Eo) * (Ec + 1.0f));
                hv[u] = hn;
                if (t < TSTEPS - 1) {
                    // scatter h (fp16) into next timestep's A-fragment slots
                    const int lp = (q * 4 + r) + 16 * (2 * (gr & 1) + (m >> 3));
                    hb[(gr >> 1) * 512 + lp * 8 + (m & 7)] = (_Float16)hn;
                }
            }
        }
    }

    // ---- FC epilogue: out[e] = sum_j h[j][e] * W_fc[j] + b_fc ----
    float wfc[4];
    #pragma unroll
    for (int n = 0; n < 4; n++) wfc[n] = W_fc[n * 16 + m];
    const float bfc = b_fc[0];

    #pragma unroll
    for (int r = 0; r < 4; r++) {
        float p = hv[r] * wfc[0];
        p = fmaf(hv[4 + r],  wfc[1], p);
        p = fmaf(hv[8 + r],  wfc[2], p);
        p = fmaf(hv[12 + r], wfc[3], p);
        p += __shfl_xor(p, 1, 64);
        p += __shfl_xor(p, 2, 64);
        p += __shfl_xor(p, 4, 64);
        p += __shfl_xor(p, 8, 64);
        if (m == 0) {
            const int e = eg0 + q * 4 + r;
            if (e < B) out[e] = p + bfc;
        }
    }
}

extern "C" void kernel_launch(void* const* d_in, const int* in_sizes, int n_in,
                              void* d_out, int out_size, void* d_ws, size_t ws_size,
                              hipStream_t stream) {
    const float* x    = (const float*)d_in[0];
    const float* W_ih = (const float*)d_in[1];
    const float* W_hh = (const float*)d_in[2];
    const float* b_ih = (const float*)d_in[3];
    const float* b_hh = (const float*)d_in[4];
    const float* W_fc = (const float*)d_in[5];
    const float* b_fc = (const float*)d_in[6];
    float* out = (float*)d_out;

    const int B = in_sizes[0] / TSTEPS;   // x is [B, T, 1]
    const int grid = (B + EPB - 1) / EPB;
    lstm_mfma_kernel<<<grid, BLOCK, 0, stream>>>(x, W_ih, W_hh, b_ih, b_hh,
                                                 W_fc, b_fc, out, B);
}

// Round 6
// 166.805 us; speedup vs baseline: 2.4255x; 2.4255x over previous
//
#include <hip/hip_runtime.h>

#define HDIM   64
#define TSTEPS 5
#define WAVES  16
#define BLOCK  (WAVES * 64)     // 1024 threads
#define EPW    16               // batch per wave = MFMA M
#define EPB    (WAVES * EPW)    // 256 batch per block

typedef _Float16 f16x8 __attribute__((ext_vector_type(8)));
typedef float    f32x4 __attribute__((ext_vector_type(4)));

#define L2E 1.44269504088896340736f   // log2(e)

// Native 1-ulp ops (avoid IEEE division expansion: ~7 inst + long chains each)
__device__ __forceinline__ float rcp_(float x) { return __builtin_amdgcn_rcpf(x); }
__device__ __forceinline__ float ex2_(float x) { return __builtin_amdgcn_exp2f(x); }
// sigmoid for pre-scaled argument v = x*log2(e): 1/(1+2^-v)
__device__ __forceinline__ float sigp_(float v) { return rcp_(1.0f + ex2_(-v)); }

// Gates as D[m=batch e][n=gate row j'] = A[e][k] * B[k][j'] + C(bias + x*W_ih)
// A = h^T (per-timestep, rebuilt), B = W_hh^T (staged once, PRE-SCALED by
// log2e for i/f/o columns and 2*log2e for g columns so activations use raw
// v_exp_f32 = 2^x with no multiply).
// 16x16x32 f16 layouts (verified, absmax 9.8e-4):
//   A-frag: lane holds A[m=lane&15][k = kh*32 + (lane>>4)*8 + i], i=0..7
//   B-frag: lane holds B[k = kh*32 + (lane>>4)*8 + i][n = ntile*16 + (lane&15)]
//   C/D:    lane holds D[m = (lane>>4)*4 + reg][n = ntile*16 + (lane&15)]
//
// ACTIVATION: round-0 form EXACTLY (10 trans/u, proven 60-VGPR codegen).
// Fused common-denominator variants (8 trans/u) are a DEAD END: live set
// >85 regs; cap<85 -> spill (rounds 2/3/5: 1.3-1.5 GB scratch), cap=128 ->
// half occupancy (round 4: 124 us). Do not retry without restructuring.
//
// REGISTER/OCCUPANCY MODEL (rounds 1-5, confirmed 4 points):
//   compiler VGPR cap = 256 / launch_bounds_arg2  (8->32, 4->64, 3->85, 2->128)
//   hardware residency follows ACTUAL VGPR: 60 regs -> 8 waves/SIMD possible.
//   LDS geometry is the real occupancy lever:
//     WAVES=8:  51.2 KB/block -> 3 blocks/CU x  8 waves = 24 waves/CU (6/SIMD)
//     WAVES=16: 66 KB/block   -> 2 blocks/CU x 16 waves = 32 waves/CU (8/SIMD)
//   (round-1 measured 73-77% occupancy at WAVES=16 — residency materializes;
//    it lost only because arg2=8 capped VGPR at 32 -> full spill.)
//   Hence: BLOCK=1024 with arg2=4 (cap 64, round-0 body fits at ~60).
__global__ __launch_bounds__(BLOCK, 4) void lstm_mfma_kernel(
    const float* __restrict__ x,      // [B, T, 1]
    const float* __restrict__ W_ih,   // [256, 1]
    const float* __restrict__ W_hh,   // [256, 64]
    const float* __restrict__ b_ih,   // [256]
    const float* __restrict__ b_hh,   // [256]
    const float* __restrict__ W_fc,   // [1, 64]
    const float* __restrict__ b_fc,   // [1]
    float* __restrict__ out,          // [B, 1]
    int B)
{
    __shared__ _Float16 Wf[2048 * 8];          // 32 KB, B-fragments, fragment-linear
    __shared__ _Float16 hbuf[WAVES * 1024];    // 32 KB, per-wave h A-fragments
    __shared__ float    wih_s[256];            // 1 KB (pre-scaled)
    __shared__ float    cb_s[256];             // 1 KB (pre-scaled b_ih + b_hh)

    const int tid = threadIdx.x;

    // ---- one-time staging: W_hh -> fp16 B-fragments, log2e pre-scaled ----
    #pragma unroll
    for (int s0 = 0; s0 < 2048; s0 += BLOCK) {
        const int s  = s0 + tid;
        const int ln = s & 63;
        const int kh = (s >> 6) & 1;
        const int n  = s >> 7;                             // N-tile 0..15, gate G = n>>2
        const float scl = ((n >> 2) == 2) ? (2.0f * L2E) : L2E;
        const int j  = n * 16 + (ln & 15);                 // gate row j'
        const int k0 = kh * 32 + ((ln >> 4) & 3) * 8;      // hidden k
        const float* src = W_hh + j * HDIM + k0;
        #pragma unroll
        for (int i = 0; i < 8; i++)
            Wf[s * 8 + i] = (_Float16)(src[i] * scl);
    }
    if (tid < 256) {
        const float scl = ((tid >> 6) == 2) ? (2.0f * L2E) : L2E;
        wih_s[tid] = W_ih[tid] * scl;
        cb_s[tid]  = (b_ih[tid] + b_hh[tid]) * scl;
    }
    __syncthreads();   // only barrier in the kernel

    const int lane = tid & 63;
    const int wave = tid >> 6;
    const int m    = lane & 15;    // C-layout column (gate-row local) / A row m
    const int q    = lane >> 4;    // quad
    const int eg0  = (blockIdx.x * WAVES + wave) * EPW;

    _Float16* hb = hbuf + wave * 1024;

    // x base pointers for this lane's 4 batch rows (hoisted; per-t load is imm offset)
    const float* xp[4];
    #pragma unroll
    for (int r = 0; r < 4; r++) {
        int e = eg0 + q * 4 + r;
        if (e >= B) e = B - 1;
        xp[r] = x + (long)e * TSTEPS;
    }

    float c[16];    // cell state, SCALED by 2*log2e; [gr*4+r] <-> (j=gr*16+m, e=q*4+r)
    float hv[16];   // last hidden state (unscaled), same indexing

    for (int t = 0; t < TSTEPS; t++) {
        float xt[4];
        #pragma unroll
        for (int r = 0; r < 4; r++) xt[r] = xp[r][t];

        // h A-fragments from previous timestep (same-wave LDS, no barrier needed)
        f16x8 hA0, hA1;
        if (t > 0) {
            hA0 = *(const f16x8*)(hb + lane * 8);          // kh = 0
            hA1 = *(const f16x8*)(hb + 512 + lane * 8);    // kh = 1
        }

        #pragma unroll
        for (int gr = 0; gr < 4; gr++) {       // j' chunk: j = gr*16 + m
            // C-init: bias + x*W_ih directly as the MFMA C operand
            float wihv[4], cbv[4];
            #pragma unroll
            for (int G = 0; G < 4; G++) {
                wihv[G] = wih_s[G * 64 + gr * 16 + m];   // broadcast, conflict-free
                cbv[G]  = cb_s[G * 64 + gr * 16 + m];
            }
            f32x4 ag[4];
            #pragma unroll
            for (int G = 0; G < 4; G++)
                #pragma unroll
                for (int r = 0; r < 4; r++)
                    ag[G][r] = fmaf(xt[r], wihv[G], cbv[G]);

            if (t > 0) {
                #pragma unroll
                for (int G = 0; G < 4; G++) {
                    const int n = G * 4 + gr;
                    f16x8 w0 = *(const f16x8*)(Wf + (n * 2 + 0) * 512 + lane * 8);
                    f16x8 w1 = *(const f16x8*)(Wf + (n * 2 + 1) * 512 + lane * 8);
                    ag[G] = __builtin_amdgcn_mfma_f32_16x16x32_f16(hA0, w0, ag[G], 0, 0, 0);
                    ag[G] = __builtin_amdgcn_mfma_f32_16x16x32_f16(hA1, w1, ag[G], 0, 0, 0);
                }
            }

            #pragma unroll
            for (int r = 0; r < 4; r++) {
                const int u = gr * 4 + r;
                const float si = sigp_(ag[0][r]);
                const float sf = sigp_(ag[1][r]);
                const float so = sigp_(ag[3][r]);
                // tanh(g), output pre-scaled by 2*log2e (folds the c->exp2 scale)
                const float rg  = rcp_(ex2_(ag[2][r]) + 1.0f);
                const float tgs = fmaf(rg, -4.0f * L2E, 2.0f * L2E);
                float cs = si * tgs;
                if (t > 0) cs = fmaf(sf, c[u], cs);
                c[u] = cs;                                    // scaled domain
                const float rc = rcp_(ex2_(cs) + 1.0f);       // tanh(c) = 1-2*rc
                const float hn = so * fmaf(rc, -2.0f, 1.0f);
                hv[u] = hn;
                if (t < TSTEPS - 1) {
                    // scatter h (fp16) into next timestep's A-fragment slots
                    const int lp = (q * 4 + r) + 16 * (2 * (gr & 1) + (m >> 3));
                    hb[(gr >> 1) * 512 + lp * 8 + (m & 7)] = (_Float16)hn;
                }
            }
        }
    }

    // ---- FC epilogue: out[e] = sum_j h[j][e] * W_fc[j] + b_fc ----
    float wfc[4];
    #pragma unroll
    for (int n = 0; n < 4; n++) wfc[n] = W_fc[n * 16 + m];
    const float bfc = b_fc[0];

    #pragma unroll
    for (int r = 0; r < 4; r++) {
        float p = hv[r] * wfc[0];
        p = fmaf(hv[4 + r],  wfc[1], p);
        p = fmaf(hv[8 + r],  wfc[2], p);
        p = fmaf(hv[12 + r], wfc[3], p);
        p += __shfl_xor(p, 1, 64);
        p += __shfl_xor(p, 2, 64);
        p += __shfl_xor(p, 4, 64);
        p += __shfl_xor(p, 8, 64);
        if (m == 0) {
            const int e = eg0 + q * 4 + r;
            if (e < B) out[e] = p + bfc;
        }
    }
}

extern "C" void kernel_launch(void* const* d_in, const int* in_sizes, int n_in,
                              void* d_out, int out_size, void* d_ws, size_t ws_size,
                              hipStream_t stream) {
    const float* x    = (const float*)d_in[0];
    const float* W_ih = (const float*)d_in[1];
    const float* W_hh = (const float*)d_in[2];
    const float* b_ih = (const float*)d_in[3];
    const float* b_hh = (const float*)d_in[4];
    const float* W_fc = (const float*)d_in[5];
    const float* b_fc = (const float*)d_in[6];
    float* out = (float*)d_out;

    const int B = in_sizes[0] / TSTEPS;   // x is [B, T, 1]
    const int grid = (B + EPB - 1) / EPB;
    lstm_mfma_kernel<<<grid, BLOCK, 0, stream>>>(x, W_ih, W_hh, b_ih, b_hh,
                                                 W_fc, b_fc, out, B);
}

// Round 7
// 152.718 us; speedup vs baseline: 2.6492x; 1.0922x over previous
//
#include <hip/hip_runtime.h>

#define HDIM   64
#define TSTEPS 5
#define WAVES  8
#define BLOCK  (WAVES * 64)     // 512 threads
#define EPW    16               // batch per wave = MFMA M
#define EPB    (WAVES * EPW)    // 128 batch per block

typedef _Float16 f16x8 __attribute__((ext_vector_type(8)));
typedef float    f32x4 __attribute__((ext_vector_type(4)));

#define L2E 1.44269504088896340736f   // log2(e)

// Native 1-ulp ops (trans pipe, quarter rate -> minimize count)
__device__ __forceinline__ float rcp_(float x) { return __builtin_amdgcn_rcpf(x); }
__device__ __forceinline__ float ex2_(float x) { return __builtin_amdgcn_exp2f(x); }
// sigmoid for pre-scaled argument v = x*log2(e): 1/(1+2^-v)
__device__ __forceinline__ float sigp_(float v) { return rcp_(1.0f + ex2_(-v)); }

// Gates as D[m=batch e][n=gate row j'] = A[e][k] * B[k][j'] + C(bias + x*W_ih)
// A = h^T (per-timestep, rebuilt), B = W_hh^T (staged once, PRE-SCALED by
// log2e for i/f/o columns and 2*log2e for g columns).
// 16x16x32 f16 layouts (verified, absmax 9.8e-4):
//   A-frag: lane holds A[m=lane&15][k = kh*32 + (lane>>4)*8 + i], i=0..7
//   B-frag: lane holds B[k = kh*32 + (lane>>4)*8 + i][n = ntile*16 + (lane&15)]
//   C/D:    lane holds D[m = (lane>>4)*4 + reg][n = ntile*16 + (lane&15)]
//
// ACTIVATION (this round): 8 trans/u via two LOCAL fusions, funded by killing
// the hv[16] dead weight (FC accumulated inline at t=4, W_fc staged in LDS):
//   it = i*tanh(g)*2L2E = 2L2E*(Eg-1)*rcp((1+Ei)(Eg+1))   (1 rcp, was 2)
//   sf = sigp(vf)                                          (standalone: mult. of c)
//   cs = fmaf(sf, c, it)      [c in 2L2E-scaled domain]
//   hn = o*tanh(c) = (Ec-1)*rcp((1+Eo)(Ec+1))             (1 rcp, was 2)
// sched_barrier(0) after each gr's activation caps cross-gr live-range
// interleaving (rounds 2/3/5 lesson: fused forms spilled at ~90-100 live regs).
//
// REGISTER/OCCUPANCY MODEL (rounds 1-6, confirmed):
//   compiler VGPR cap = 256/arg2  (8->32, 4->64, 3->85, 2->128)
//   HW residency: waves/CU = 2048/VGPR, halves AT 64 (round-6: VGPR=64 ->
//   4 waves/SIMD, dur 119 us > round-0's 106 despite 2x waves/block).
//   LDS 51.2 KB -> 3 blocks/CU x 8 waves = 24 waves/CU for VGPR<=85.
//   arg2=3 (cap 85): fused live set ~95-16(hv) ~= 79 should fit.
//   DEAD ENDS: WAVES=16 (VGPR=64 residency cliff); arg2=2 (VGPR 124, half
//   occupancy); register-hoisted coeff arrays (+32 live regs -> spill).
__global__ __launch_bounds__(BLOCK, 3) void lstm_mfma_kernel(
    const float* __restrict__ x,      // [B, T, 1]
    const float* __restrict__ W_ih,   // [256, 1]
    const float* __restrict__ W_hh,   // [256, 64]
    const float* __restrict__ b_ih,   // [256]
    const float* __restrict__ b_hh,   // [256]
    const float* __restrict__ W_fc,   // [1, 64]
    const float* __restrict__ b_fc,   // [1]
    float* __restrict__ out,          // [B, 1]
    int B)
{
    __shared__ _Float16 Wf[2048 * 8];          // 32 KB, B-fragments, fragment-linear
    __shared__ _Float16 hbuf[WAVES * 1024];    // 16 KB, per-wave h A-fragments
    __shared__ float    wih_s[256];            // 1 KB (pre-scaled)
    __shared__ float    cb_s[256];             // 1 KB (pre-scaled b_ih + b_hh)
    __shared__ float    wfc_s[64];             // 256 B (FC weights)

    const int tid = threadIdx.x;

    // ---- one-time staging: W_hh -> fp16 B-fragments, log2e pre-scaled ----
    #pragma unroll
    for (int s0 = 0; s0 < 2048; s0 += BLOCK) {
        const int s  = s0 + tid;
        const int ln = s & 63;
        const int kh = (s >> 6) & 1;
        const int n  = s >> 7;                             // N-tile 0..15, gate G = n>>2
        const float scl = ((n >> 2) == 2) ? (2.0f * L2E) : L2E;
        const int j  = n * 16 + (ln & 15);                 // gate row j'
        const int k0 = kh * 32 + ((ln >> 4) & 3) * 8;      // hidden k
        const float* src = W_hh + j * HDIM + k0;
        #pragma unroll
        for (int i = 0; i < 8; i++)
            Wf[s * 8 + i] = (_Float16)(src[i] * scl);
    }
    if (tid < 256) {
        const float scl = ((tid >> 6) == 2) ? (2.0f * L2E) : L2E;
        wih_s[tid] = W_ih[tid] * scl;
        cb_s[tid]  = (b_ih[tid] + b_hh[tid]) * scl;
    }
    if (tid < 64) wfc_s[tid] = W_fc[tid];
    __syncthreads();   // only barrier in the kernel

    const int lane = tid & 63;
    const int wave = tid >> 6;
    const int m    = lane & 15;    // C-layout column (gate-row local) / A row m
    const int q    = lane >> 4;    // quad
    const int eg0  = (blockIdx.x * WAVES + wave) * EPW;

    _Float16* hb = hbuf + wave * 1024;

    // x base pointers for this lane's 4 batch rows (hoisted; per-t load is imm offset)
    const float* xp[4];
    #pragma unroll
    for (int r = 0; r < 4; r++) {
        int e = eg0 + q * 4 + r;
        if (e >= B) e = B - 1;
        xp[r] = x + (long)e * TSTEPS;
    }

    float c[16];    // cell state, SCALED by 2*log2e; [gr*4+r] <-> (j=gr*16+m, e=q*4+r)
    float pfc[4];   // FC partial sums, defined only in the t=4 body

    #pragma unroll
    for (int t = 0; t < TSTEPS; t++) {
        float xt[4];
        #pragma unroll
        for (int r = 0; r < 4; r++) xt[r] = xp[r][t];

        // h A-fragments from previous timestep (same-wave LDS, no barrier needed)
        f16x8 hA0, hA1;
        if (t > 0) {
            hA0 = *(const f16x8*)(hb + lane * 8);          // kh = 0
            hA1 = *(const f16x8*)(hb + 512 + lane * 8);    // kh = 1
        }

        #pragma unroll
        for (int gr = 0; gr < 4; gr++) {       // j' chunk: j = gr*16 + m
            // C-init: bias + x*W_ih directly as the MFMA C operand
            float wihv[4], cbv[4];
            #pragma unroll
            for (int G = 0; G < 4; G++) {
                wihv[G] = wih_s[G * 64 + gr * 16 + m];   // broadcast, conflict-free
                cbv[G]  = cb_s[G * 64 + gr * 16 + m];
            }
            f32x4 ag[4];
            #pragma unroll
            for (int G = 0; G < 4; G++)
                #pragma unroll
                for (int r = 0; r < 4; r++)
                    ag[G][r] = fmaf(xt[r], wihv[G], cbv[G]);

            if (t > 0) {
                #pragma unroll
                for (int G = 0; G < 4; G++) {
                    const int n = G * 4 + gr;
                    f16x8 w0 = *(const f16x8*)(Wf + (n * 2 + 0) * 512 + lane * 8);
                    f16x8 w1 = *(const f16x8*)(Wf + (n * 2 + 1) * 512 + lane * 8);
                    ag[G] = __builtin_amdgcn_mfma_f32_16x16x32_f16(hA0, w0, ag[G], 0, 0, 0);
                    ag[G] = __builtin_amdgcn_mfma_f32_16x16x32_f16(hA1, w1, ag[G], 0, 0, 0);
                }
            }

            #pragma unroll
            for (int r = 0; r < 4; r++) {
                const int u = gr * 4 + r;
                // fused i*tanh(g): 2 ex2 + 1 rcp
                const float Ei = ex2_(-ag[0][r]);
                const float Eg = ex2_(ag[2][r]);
                const float it = (2.0f * L2E) * (Eg - 1.0f) *
                                 rcp_((1.0f + Ei) * (Eg + 1.0f));
                float cs = it;
                if (t > 0) {
                    const float sf = sigp_(ag[1][r]);     // 1 ex2 + 1 rcp
                    cs = fmaf(sf, c[u], it);
                }
                c[u] = cs;                                // scaled domain
                // fused o*tanh(c): 2 ex2 + 1 rcp
                const float Eo = ex2_(-ag[3][r]);
                const float Ec = ex2_(cs);
                const float hn = (Ec - 1.0f) * rcp_((1.0f + Eo) * (Ec + 1.0f));
                if (t < TSTEPS - 1) {
                    // scatter h (fp16) into next timestep's A-fragment slots
                    const int lp = (q * 4 + r) + 16 * (2 * (gr & 1) + (m >> 3));
                    hb[(gr >> 1) * 512 + lp * 8 + (m & 7)] = (_Float16)hn;
                } else {
                    // FC inline: pfc[r] += h[j=gr*16+m][e] * W_fc[j]
                    const float w = wfc_s[gr * 16 + m];
                    pfc[r] = (gr == 0) ? hn * w : fmaf(hn, w, pfc[r]);
                }
            }
            // cap cross-gr live-range interleaving (anti-spill fence)
            __builtin_amdgcn_sched_barrier(0);
        }
    }

    // ---- FC epilogue: reduce pfc over the 16 m-lanes, write out ----
    const float bfc = b_fc[0];
    #pragma unroll
    for (int r = 0; r < 4; r++) {
        float p = pfc[r];
        p += __shfl_xor(p, 1, 64);
        p += __shfl_xor(p, 2, 64);
        p += __shfl_xor(p, 4, 64);
        p += __shfl_xor(p, 8, 64);
        if (m == 0) {
            const int e = eg0 + q * 4 + r;
            if (e < B) out[e] = p + bfc;
        }
    }
}

extern "C" void kernel_launch(void* const* d_in, const int* in_sizes, int n_in,
                              void* d_out, int out_size, void* d_ws, size_t ws_size,
                              hipStream_t stream) {
    const float* x    = (const float*)d_in[0];
    const float* W_ih = (const float*)d_in[1];
    const float* W_hh = (const float*)d_in[2];
    const float* b_ih = (const float*)d_in[3];
    const float* b_hh = (const float*)d_in[4];
    const float* W_fc = (const float*)d_in[5];
    const float* b_fc = (const float*)d_in[6];
    float* out = (float*)d_out;

    const int B = in_sizes[0] / TSTEPS;   // x is [B, T, 1]
    const int grid = (B + EPB - 1) / EPB;
    lstm_mfma_kernel<<<grid, BLOCK, 0, stream>>>(x, W_ih, W_hh, b_ih, b_hh,
                                                 W_fc, b_fc, out, B);
}

// Round 8
// 150.608 us; speedup vs baseline: 2.6863x; 1.0140x over previous
//
#include <hip/hip_runtime.h>

#define HDIM   64
#define TSTEPS 5
#define WAVES  8
#define BLOCK  (WAVES * 64)     // 512 threads
#define EPW    16               // batch per wave = MFMA M
#define EPB    (WAVES * EPW)    // 128 batch per block

typedef _Float16 f16x8 __attribute__((ext_vector_type(8)));
typedef float    f32x4 __attribute__((ext_vector_type(4)));

#define L2E 1.44269504088896340736f   // log2(e)

// Native 1-ulp ops (trans pipe, quarter rate -> minimize count)
__device__ __forceinline__ float rcp_(float x) { return __builtin_amdgcn_rcpf(x); }
__device__ __forceinline__ float ex2_(float x) { return __builtin_amdgcn_exp2f(x); }

// Gates as D[m=batch e][n=gate row j'] = A[e][k] * B[k][j'] + C(bias + x*W_ih)
// A = h^T (per-timestep, rebuilt), B = W_hh^T (staged once, PRE-SCALED by
// log2e for i/f/o columns and 2*log2e for g columns).
// 16x16x32 f16 layouts (verified, absmax 9.8e-4):
//   A-frag: lane holds A[m=lane&15][k = kh*32 + (lane>>4)*8 + i], i=0..7
//   B-frag: lane holds B[k = kh*32 + (lane>>4)*8 + i][n = ntile*16 + (lane&15)]
//   C/D:    lane holds D[m = (lane>>4)*4 + reg][n = ntile*16 + (lane&15)]
//
// ACTIVATION (7 trans/u): two local fusions + PAIRED rcp:
//   a  = (1+Ei)(Eg+1);  b = (1+Ef);  rr = rcp(a*b)       // ONE rcp for i&f
//   it = 2L2E*(Eg-1)*(rr*b)   [= i*tanh(g), scaled]
//   sf = rr*a                 [= sigmoid(f)]
//   cs = fmaf(sf, c, it)      [c in 2L2E-scaled domain]
//   hn = (Ec-1)*rcp((1+Eo)(Ec+1))                        // o*tanh(c)
// -> 5 ex2 + 2 rcp (t>0). Round-0 was 5 ex2 + 5 rcp.
// hv[16] dead weight removed: FC accumulated inline at t=4 (W_fc in LDS).
//
// REGISTER/OCCUPANCY MODEL (rounds 1-7, confirmed):
//   compiler VGPR cap = 256/arg2  (8->32, 4->64, 3->85, 2->128)
//   HW residency cliff AT 64 VGPR: <=63 -> 8 waves/SIMD possible; 64-128 -> 4.
//   (r4: VGPR 124 -> occ 19%, dur 124; r6: VGPR 64 -> occ 31%, dur 119;
//    r0/r7: VGPR 56-60 -> occ 35-36%, dur 105-106.)
//   LDS 51.2 KB -> 3 blocks/CU x 8 waves = 24 waves/CU.
//   arg2=4 pins cap at 64: round-7 body fits at 56; the freed scheduler
//   (sched_barriers REMOVED this round: they forbade gr+1 MFMA/ds_read
//   overlap with gr activation VALU and cost ~5%) cannot balloon past the
//   cliff. DEAD ENDS: WAVES=16; arg2<=3 with >64 live; hoisted coeff arrays;
//   global common-denominator activation (live set ~95+).
__global__ __launch_bounds__(BLOCK, 4) void lstm_mfma_kernel(
    const float* __restrict__ x,      // [B, T, 1]
    const float* __restrict__ W_ih,   // [256, 1]
    const float* __restrict__ W_hh,   // [256, 64]
    const float* __restrict__ b_ih,   // [256]
    const float* __restrict__ b_hh,   // [256]
    const float* __restrict__ W_fc,   // [1, 64]
    const float* __restrict__ b_fc,   // [1]
    float* __restrict__ out,          // [B, 1]
    int B)
{
    __shared__ _Float16 Wf[2048 * 8];          // 32 KB, B-fragments, fragment-linear
    __shared__ _Float16 hbuf[WAVES * 1024];    // 16 KB, per-wave h A-fragments
    __shared__ float    wih_s[256];            // 1 KB (pre-scaled)
    __shared__ float    cb_s[256];             // 1 KB (pre-scaled b_ih + b_hh)
    __shared__ float    wfc_s[64];             // 256 B (FC weights)

    const int tid = threadIdx.x;

    // ---- one-time staging: W_hh -> fp16 B-fragments, log2e pre-scaled ----
    #pragma unroll
    for (int s0 = 0; s0 < 2048; s0 += BLOCK) {
        const int s  = s0 + tid;
        const int ln = s & 63;
        const int kh = (s >> 6) & 1;
        const int n  = s >> 7;                             // N-tile 0..15, gate G = n>>2
        const float scl = ((n >> 2) == 2) ? (2.0f * L2E) : L2E;
        const int j  = n * 16 + (ln & 15);                 // gate row j'
        const int k0 = kh * 32 + ((ln >> 4) & 3) * 8;      // hidden k
        const float* src = W_hh + j * HDIM + k0;
        #pragma unroll
        for (int i = 0; i < 8; i++)
            Wf[s * 8 + i] = (_Float16)(src[i] * scl);
    }
    if (tid < 256) {
        const float scl = ((tid >> 6) == 2) ? (2.0f * L2E) : L2E;
        wih_s[tid] = W_ih[tid] * scl;
        cb_s[tid]  = (b_ih[tid] + b_hh[tid]) * scl;
    }
    if (tid < 64) wfc_s[tid] = W_fc[tid];
    __syncthreads();   // only barrier in the kernel

    const int lane = tid & 63;
    const int wave = tid >> 6;
    const int m    = lane & 15;    // C-layout column (gate-row local) / A row m
    const int q    = lane >> 4;    // quad
    const int eg0  = (blockIdx.x * WAVES + wave) * EPW;

    _Float16* hb = hbuf + wave * 1024;

    // Single x base pointer; per-(r,t) loads are compile-time imm offsets.
    // Clamp the 4-row window into [0, B): rows >= B compute garbage on valid
    // memory; the out-write guard drops them.
    int e0 = eg0 + q * 4;
    if (e0 > B - 4) e0 = (B >= 4 ? B - 4 : 0);
    const float* xp0 = x + (long)e0 * TSTEPS;

    float c[16];    // cell state, SCALED by 2*log2e; [gr*4+r] <-> (j=gr*16+m, e=e0+r)
    float pfc[4];   // FC partial sums, defined only in the t=4 body

    #pragma unroll
    for (int t = 0; t < TSTEPS; t++) {
        float xt[4];
        #pragma unroll
        for (int r = 0; r < 4; r++) xt[r] = xp0[r * TSTEPS + t];   // imm offsets

        // h A-fragments from previous timestep (same-wave LDS, no barrier needed)
        f16x8 hA0, hA1;
        if (t > 0) {
            hA0 = *(const f16x8*)(hb + lane * 8);          // kh = 0
            hA1 = *(const f16x8*)(hb + 512 + lane * 8);    // kh = 1
        }

        #pragma unroll
        for (int gr = 0; gr < 4; gr++) {       // j' chunk: j = gr*16 + m
            // C-init: bias + x*W_ih directly as the MFMA C operand
            float wihv[4], cbv[4];
            #pragma unroll
            for (int G = 0; G < 4; G++) {
                wihv[G] = wih_s[G * 64 + gr * 16 + m];   // broadcast, conflict-free
                cbv[G]  = cb_s[G * 64 + gr * 16 + m];
            }
            f32x4 ag[4];
            #pragma unroll
            for (int G = 0; G < 4; G++)
                #pragma unroll
                for (int r = 0; r < 4; r++)
                    ag[G][r] = fmaf(xt[r], wihv[G], cbv[G]);

            if (t > 0) {
                #pragma unroll
                for (int G = 0; G < 4; G++) {
                    const int n = G * 4 + gr;
                    f16x8 w0 = *(const f16x8*)(Wf + (n * 2 + 0) * 512 + lane * 8);
                    f16x8 w1 = *(const f16x8*)(Wf + (n * 2 + 1) * 512 + lane * 8);
                    ag[G] = __builtin_amdgcn_mfma_f32_16x16x32_f16(hA0, w0, ag[G], 0, 0, 0);
                    ag[G] = __builtin_amdgcn_mfma_f32_16x16x32_f16(hA1, w1, ag[G], 0, 0, 0);
                }
            }

            #pragma unroll
            for (int r = 0; r < 4; r++) {
                const int u = gr * 4 + r;
                const float Ei = ex2_(-ag[0][r]);
                const float Eg = ex2_(ag[2][r]);
                const float a  = (1.0f + Ei) * (Eg + 1.0f);
                const float gn = (2.0f * L2E) * (Eg - 1.0f);
                float cs;
                if (t > 0) {
                    // paired rcp: one v_rcp serves both i*tanh(g) and sigmoid(f)
                    const float Ef = ex2_(-ag[1][r]);
                    const float b  = 1.0f + Ef;
                    const float rr = rcp_(a * b);
                    const float it = gn * (rr * b);
                    const float sf = rr * a;
                    cs = fmaf(sf, c[u], it);
                } else {
                    cs = gn * rcp_(a);
                }
                c[u] = cs;                                // scaled domain
                // fused o*tanh(c): 2 ex2 + 1 rcp
                const float Eo = ex2_(-ag[3][r]);
                const float Ec = ex2_(cs);
                const float hn = (Ec - 1.0f) * rcp_((1.0f + Eo) * (Ec + 1.0f));
                if (t < TSTEPS - 1) {
                    // scatter h (fp16) into next timestep's A-fragment slots
                    const int lp = (q * 4 + r) + 16 * (2 * (gr & 1) + (m >> 3));
                    hb[(gr >> 1) * 512 + lp * 8 + (m & 7)] = (_Float16)hn;
                } else {
                    // FC inline: pfc[r] += h[j=gr*16+m][e] * W_fc[j]
                    const float w = wfc_s[gr * 16 + m];
                    pfc[r] = (gr == 0) ? hn * w : fmaf(hn, w, pfc[r]);
                }
            }
        }
    }

    // ---- FC epilogue: reduce pfc over the 16 m-lanes, write out ----
    const float bfc = b_fc[0];
    #pragma unroll
    for (int r = 0; r < 4; r++) {
        float p = pfc[r];
        p += __shfl_xor(p, 1, 64);
        p += __shfl_xor(p, 2, 64);
        p += __shfl_xor(p, 4, 64);
        p += __shfl_xor(p, 8, 64);
        if (m == 0) {
            const int e = e0 + r;
            if (e < B) out[e] = p + bfc;
        }
    }
}

extern "C" void kernel_launch(void* const* d_in, const int* in_sizes, int n_in,
                              void* d_out, int out_size, void* d_ws, size_t ws_size,
                              hipStream_t stream) {
    const float* x    = (const float*)d_in[0];
    const float* W_ih = (const float*)d_in[1];
    const float* W_hh = (const float*)d_in[2];
    const float* b_ih = (const float*)d_in[3];
    const float* b_hh = (const float*)d_in[4];
    const float* W_fc = (const float*)d_in[5];
    const float* b_fc = (const float*)d_in[6];
    float* out = (float*)d_out;

    const int B = in_sizes[0] / TSTEPS;   // x is [B, T, 1]
    const int grid = (B + EPB - 1) / EPB;
    lstm_mfma_kernel<<<grid, BLOCK, 0, stream>>>(x, W_ih, W_hh, b_ih, b_hh,
                                                 W_fc, b_fc, out, B);
}